// Round 15
// baseline (211.537 us; speedup 1.0000x reference)
//
#include <hip/hip_runtime.h>

// ---------------------------------------------------------------------------
// DrugGCN, bf16-MFMA pipeline (R15 = R14 + MCHUNK=4 + fused tail reduce):
//   k_count: rank[e] = atomicAdd(&counts[dst],1)   (rank is free)
//   k_prep2: [fill_csr | cvt_x | cvt_w] one dispatch (complementary regimes)
//   g1  = A_hat xb           (R8 gather FROZEN: 16-lane groups, 4 strided
//   a1r = relu(g1@W1 + b1)    nodes, 1-ahead pipeline)
//   g2  = A_hat a1r
//   out = mean_rows relu(g2@W2 + b2)  (B-stationary GEMM, fused col-reduce)
//   k_reduce: 16 blocks -> p2; ticket counter; last block does final sum
//             (fixed-order loop -> deterministic)
// ---------------------------------------------------------------------------

typedef __attribute__((ext_vector_type(8))) short short8;
typedef __attribute__((ext_vector_type(4))) float f32x4;

__device__ __forceinline__ float b2f(unsigned short u) {
    union { unsigned int i; float f; } c;
    c.i = ((unsigned int)u) << 16;
    return c.f;
}
__device__ __forceinline__ unsigned short f2b(float x) {
    union { float f; unsigned int i; } c;
    c.f = x;
    unsigned int r = c.i + 0x7FFFu + ((c.i >> 16) & 1u);   // RNE
    return (unsigned short)(r >> 16);
}

__device__ __forceinline__ int edge_idx(const void* ei, int is64, int which,
                                        int E, int e) {
    if (is64) return (int)((const long long*)ei)[(size_t)which * E + e];
    return ((const int*)ei)[(size_t)which * E + e];
}

// --- init: zero counts + ticket; block 0 runs the sampled dtype detector ----
__global__ void k_init(const int* __restrict__ ei, int E, int* __restrict__ counts,
                       int* __restrict__ flag, int N) {
    int i = blockIdx.x * 256 + threadIdx.x;
    if (i < N) counts[i] = 0;
    if (blockIdx.x == 0) {
        __shared__ int anyv[4];
        int t = threadIdx.x;
        if (t == 1) flag[1] = 0;                 // reduce ticket
        int v = 0;
#pragma unroll
        for (int r = 0; r < 4; ++r) {
            long long k = (long long)(t * 4 + r) * E >> 10;   // spread over [0,E)
            v |= ei[2 * (int)k + 1];
        }
        unsigned long long m = __ballot(v != 0);
        if ((t & 63) == 0) anyv[t >> 6] = (m != 0ull) ? 1 : 0;
        __syncthreads();
        if (t == 0) flag[0] = anyv[0] | anyv[1] | anyv[2] | anyv[3];
    }
}

// --- count + per-edge rank (atomicAdd return value is free) -----------------
__global__ void k_count(const void* __restrict__ ei, const int* __restrict__ flag,
                        int* __restrict__ counts, int* __restrict__ rank, int E) {
    int e = blockIdx.x * 256 + threadIdx.x;
    if (e >= E) return;
    int is64 = (*flag == 0);
    int d = edge_idx(ei, is64, 1, E, e);
    rank[e] = atomicAdd(&counts[d], 1);
}

// --- scan1 (+ fused dinv): per-block exclusive scan of counts ---------------
__global__ void k_scan1(const int* __restrict__ counts, int* __restrict__ offs,
                        int* __restrict__ blockSums, float* __restrict__ dinv,
                        int n) {
    __shared__ int tmp[256];
    int t = threadIdx.x;
    int i = blockIdx.x * 256 + t;
    int my = (i < n) ? counts[i] : 0;
    if (i < n) dinv[i] = rsqrtf(1.0f + (float)my);
    tmp[t] = my;
    __syncthreads();
    for (int off = 1; off < 256; off <<= 1) {
        int v = (t >= off) ? tmp[t - off] : 0;
        __syncthreads();
        tmp[t] += v;
        __syncthreads();
    }
    if (i < n) offs[i] = tmp[t] - my;
    if (t == 255) blockSums[blockIdx.x] = tmp[255];
}

// single-block 512-thread Hillis-Steele scan (exclusive), carry over tiles
__global__ void k_scan2(int* __restrict__ blockSums, int nb) {
    __shared__ int tmp[512];
    __shared__ int carry;
    int t = threadIdx.x;
    if (t == 0) carry = 0;
    __syncthreads();
    for (int base = 0; base < nb; base += 512) {
        int i = base + t;
        int my = (i < nb) ? blockSums[i] : 0;
        tmp[t] = my;
        __syncthreads();
        for (int off = 1; off < 512; off <<= 1) {
            int v = (t >= off) ? tmp[t - off] : 0;
            __syncthreads();
            tmp[t] += v;
            __syncthreads();
        }
        if (i < nb) blockSums[i] = carry + tmp[t] - my;   // exclusive
        __syncthreads();
        if (t == 0) carry += tmp[511];
        __syncthreads();
    }
}

__global__ void k_scan3(int* __restrict__ offs, const int* __restrict__ blockSums,
                        int n) {
    int i = blockIdx.x * 256 + threadIdx.x;
    if (i < n) offs[i] += blockSums[blockIdx.x];
}

// --- fused prep: [fill_csr | cvt_x | cvt_w] by blockIdx range ---------------
__global__ void k_prep2(const void* __restrict__ ei, const int* __restrict__ flag,
                        const float* __restrict__ dinv,
                        const int* __restrict__ offs, const int* __restrict__ rank,
                        int2* __restrict__ csr2, int E, int FB,
                        const float* __restrict__ x, unsigned short* __restrict__ xb,
                        int n4x, int XB,
                        const float* __restrict__ W1, const float* __restrict__ W2,
                        unsigned short* __restrict__ wt1,
                        unsigned short* __restrict__ wt2) {
    const int b = blockIdx.x;
    if (b < FB) {                                   // --- CSR fill ---
        int e = b * 256 + threadIdx.x;
        if (e >= E) return;
        int is64 = (*flag == 0);
        int s = edge_idx(ei, is64, 0, E, e);
        int d = edge_idx(ei, is64, 1, E, e);
        int pos = offs[d] + rank[e];
        csr2[pos] = make_int2(s, __float_as_int(dinv[s] * dinv[d]));
    } else if (b < FB + XB) {                       // --- x -> bf16 ---
        int i = (b - FB) * 256 + threadIdx.x;
        if (i >= n4x) return;
        float4 v = reinterpret_cast<const float4*>(x)[i];
        ushort4 o;
        o.x = f2b(v.x); o.y = f2b(v.y); o.z = f2b(v.z); o.w = f2b(v.w);
        reinterpret_cast<ushort4*>(xb)[i] = o;
    } else {                                        // --- weights -> WT bf16 ---
        int idx = (b - FB - XB) * 256 + threadIdx.x;
        if (idx < 128 * 128) {
            int k = idx >> 7, n = idx & 127;        // KOUT=128
            wt1[(size_t)n * 128 + k] = f2b(W1[idx]);
        } else if (idx < 128 * 128 + 128 * 256) {
            int i2 = idx - 128 * 128;
            int k = i2 >> 8, n = i2 & 255;          // KOUT=256
            wt2[(size_t)n * 128 + k] = f2b(W2[i2]);
        }
    }
}

// --- CSR gather (R8 EXACT: 16-lane groups, strided nodes, 1-ahead pipe) -----
template <int CHUNK>
__global__ __launch_bounds__(256) void k_gather_b(const unsigned short* __restrict__ h,
                                                  const float* __restrict__ dinv,
                                                  const int* __restrict__ offs,
                                                  const int* __restrict__ counts,
                                                  const int2* __restrict__ csr2,
                                                  unsigned short* __restrict__ g,
                                                  int N) {
    const int grp = threadIdx.x >> 4, l16 = threadIdx.x & 15;
    const short8* h8 = reinterpret_cast<const short8*>(h);
    const int base = blockIdx.x * (CHUNK * 16) + grp;

    for (int i = 0; i < CHUNK; ++i) {
        const int node = base + i * 16;
        if (node >= N) break;               // uniform across the 16-lane group
        const float dd = dinv[node];
        const float w0 = dd * dd;
        const size_t rowu = (size_t)node * 16 + l16;
        short8 sv = h8[rowu];
        float a[8];
#pragma unroll
        for (int j = 0; j < 8; ++j) a[j] = b2f((unsigned short)sv[j]) * w0;

        const int beg = offs[node], cnt = counts[node];
        if (cnt > 0) {
            int2 p = csr2[beg];
            short8 v = h8[(size_t)p.x * 16 + l16];
            for (int e = 1; e < cnt; ++e) {
                int2 pn = csr2[beg + e];                       // next pair
                short8 vn = h8[(size_t)pn.x * 16 + l16];       // next row (issued
                float w = __int_as_float(p.y);                 //  before acc wait)
#pragma unroll
                for (int j = 0; j < 8; ++j)
                    a[j] = fmaf(b2f((unsigned short)v[j]), w, a[j]);
                p = pn; v = vn;
            }
            float w = __int_as_float(p.y);
#pragma unroll
            for (int j = 0; j < 8; ++j)
                a[j] = fmaf(b2f((unsigned short)v[j]), w, a[j]);
        }
        short8 o;
#pragma unroll
        for (int j = 0; j < 8; ++j) o[j] = (short)f2b(a[j]);
        reinterpret_cast<short8*>(g)[rowu] = o;
    }
}

// --- B-stationary MFMA GEMM (R7/R8 body; MCHUNK=4 grid) ---------------------
// Fragment mapping (16x16x32, m89-verified): A: row=lane&15, k=(lane>>4)*8+j;
// B: col=lane&15 (WT row), same k; D: col=lane&15, row=(lane>>4)*4+r.
template <int KOUT, bool REDUCE, int CHUNK>
__global__ __launch_bounds__(256) void k_mgemm(const unsigned short* __restrict__ A,
                                               const unsigned short* __restrict__ WT,
                                               const float* __restrict__ bias,
                                               unsigned short* __restrict__ C,
                                               float* __restrict__ partials, int N) {
    constexpr int NFW = KOUT / 64;       // col-frags per wave (2 or 4)
    const int tid = threadIdx.x;
    const int wave = tid >> 6, lane = tid & 63;
    const int l15 = lane & 15, lg = lane >> 4;
    const int colbase = wave * (KOUT / 4);

    short8 breg[NFW][4];
    float bv[NFW];
#pragma unroll
    for (int nf = 0; nf < NFW; ++nf) {
        int col = colbase + nf * 16 + l15;
        bv[nf] = bias[col];
#pragma unroll
        for (int kk = 0; kk < 4; ++kk)
            breg[nf][kk] = *reinterpret_cast<const short8*>(
                WT + (size_t)col * 128 + kk * 32 + lg * 8);
    }

    float psum[NFW];
#pragma unroll
    for (int nf = 0; nf < NFW; ++nf) psum[nf] = 0.f;

    const int NT = (N + 15) / 16;
    const int t0 = blockIdx.x * CHUNK;
    const int tend = (t0 + CHUNK < NT) ? t0 + CHUNK : NT;

#pragma unroll 2
    for (int t = t0; t < tend; ++t) {
        const int rows = t * 16;
        const int arow = rows + l15;
        short8 a[4];
        const bool rv = arow < N;
#pragma unroll
        for (int kk = 0; kk < 4; ++kk)
            a[kk] = rv ? *reinterpret_cast<const short8*>(
                             A + (size_t)arow * 128 + kk * 32 + lg * 8)
                       : (short8){0, 0, 0, 0, 0, 0, 0, 0};

        f32x4 acc[NFW];
#pragma unroll
        for (int nf = 0; nf < NFW; ++nf) acc[nf] = (f32x4){0.f, 0.f, 0.f, 0.f};
#pragma unroll
        for (int kk = 0; kk < 4; ++kk)
#pragma unroll
            for (int nf = 0; nf < NFW; ++nf)
                acc[nf] = __builtin_amdgcn_mfma_f32_16x16x32_bf16(
                    a[kk], breg[nf][kk], acc[nf], 0, 0, 0);

        if (!REDUCE) {
#pragma unroll
            for (int nf = 0; nf < NFW; ++nf) {
                int col = colbase + nf * 16 + l15;
#pragma unroll
                for (int r = 0; r < 4; ++r) {
                    int rr = rows + lg * 4 + r;
                    if (rr < N)
                        C[(size_t)rr * KOUT + col] =
                            f2b(fmaxf(acc[nf][r] + bv[nf], 0.f));
                }
            }
        } else {
#pragma unroll
            for (int nf = 0; nf < NFW; ++nf) {
#pragma unroll
                for (int r = 0; r < 4; ++r) {
                    int rr = rows + lg * 4 + r;
                    if (rr < N) psum[nf] += fmaxf(acc[nf][r] + bv[nf], 0.f);
                }
            }
        }
    }

    if (REDUCE) {
#pragma unroll
        for (int nf = 0; nf < NFW; ++nf) {
            float s = psum[nf];
            s += __shfl_xor(s, 16);
            s += __shfl_xor(s, 32);
            if (lg == 0)
                partials[(size_t)blockIdx.x * KOUT + colbase + nf * 16 + l15] = s;
        }
    }
}

// --- fused partials reduction: 16 blocks -> p2; last block -> out -----------
// ticket = flag[1] (zeroed in k_init). Final sum is a fixed-order 16-iter
// loop per column -> deterministic.
__global__ void k_reduce(const float* __restrict__ partials, float* __restrict__ p2,
                         float* __restrict__ out, int* __restrict__ ticket,
                         int NB, float invN) {
    __shared__ int lastdone;
    int c = threadIdx.x;
    float sum = 0.f;
    for (int r = blockIdx.x; r < NB; r += 16)
        sum += partials[(size_t)r * 256 + c];
    p2[blockIdx.x * 256 + c] = sum;
    __threadfence();                    // publish p2 before ticket
    __syncthreads();
    if (c == 0) lastdone = (atomicAdd(ticket, 1) == 15);
    __syncthreads();
    if (lastdone) {
        float s = 0.f;
#pragma unroll
        for (int b = 0; b < 16; ++b) s += p2[b * 256 + c];
        out[c] = s * invN;
    }
}

// ---------------------------------------------------------------------------
extern "C" void kernel_launch(void* const* d_in, const int* in_sizes, int n_in,
                              void* d_out, int out_size, void* d_ws, size_t ws_size,
                              hipStream_t stream) {
    const float* x  = (const float*)d_in[0];
    const void*  ei = d_in[1];
    const float* W1 = (const float*)d_in[2];
    const float* b1 = (const float*)d_in[3];
    const float* W2 = (const float*)d_in[4];
    const float* b2 = (const float*)d_in[5];
    float* out = (float*)d_out;

    const int N = in_sizes[0] / 128;   // 100000
    const int E = in_sizes[1] / 2;     // 600000
    const int nb = (N + 255) / 256;
    constexpr int GCHUNK = 4;          // FROZEN (R8 optimum)
    constexpr int MCHUNK = 4;          // 8->4: 1563 blocks = 6.1/CU (was 3.05)
    const int NT = (N + 15) / 16;
    const int NBLK = (NT + MCHUNK - 1) / MCHUNK;              // gemm blocks
    const int GBLK = (N + GCHUNK * 16 - 1) / (GCHUNK * 16);   // gather blocks
    const int FB = (E + 255) / 256;                           // fill blocks
    const int XB = (N * 32 + 255) / 256;                      // cvt_x blocks
    const int WB = (128 * 384 + 255) / 256;                   // cvt_w blocks

    char* ws = (char*)d_ws;
    size_t off = 0;
    auto alloc = [&](size_t bytes) {
        char* p = ws + off;
        off += (bytes + 255) & ~(size_t)255;
        return p;
    };
    int*            flag      = (int*)alloc(8);               // [0]=dtype [1]=ticket
    int*            counts    = (int*)alloc((size_t)N * 4);
    int*            offs      = (int*)alloc((size_t)N * 4);
    int*            blockSums = (int*)alloc((size_t)nb * 4);
    float*          dinv      = (float*)alloc((size_t)N * 4);
    int*            rank      = (int*)alloc((size_t)E * 4);
    int2*           csr2      = (int2*)alloc((size_t)E * 8);
    float*          partials  = (float*)alloc((size_t)NBLK * 256 * 4);
    float*          p2        = (float*)alloc((size_t)16 * 256 * 4);
    unsigned short* wt1       = (unsigned short*)alloc((size_t)128 * 128 * 2);
    unsigned short* wt2       = (unsigned short*)alloc((size_t)256 * 128 * 2);
    unsigned short* xb        = (unsigned short*)alloc((size_t)N * 128 * 2);
    unsigned short* g1        = (unsigned short*)alloc((size_t)N * 128 * 2);
    unsigned short* a1r       = (unsigned short*)alloc((size_t)N * 128 * 2);
    unsigned short* g2        = xb;    // xb dead after gather1

    // --- CSR build: init -> count(+rank) -> scan -> fused prep ---
    k_init<<<nb, 256, 0, stream>>>((const int*)ei, E, counts, flag, N);
    k_count<<<(E + 255) / 256, 256, 0, stream>>>(ei, flag, counts, rank, E);
    k_scan1<<<nb, 256, 0, stream>>>(counts, offs, blockSums, dinv, N);
    k_scan2<<<1, 512, 0, stream>>>(blockSums, nb);
    k_scan3<<<nb, 256, 0, stream>>>(offs, blockSums, N);
    k_prep2<<<FB + XB + WB, 256, 0, stream>>>(ei, flag, dinv, offs, rank, csr2,
                                              E, FB, x, xb, N * 32, XB,
                                              W1, W2, wt1, wt2);

    // --- layer 1 ---
    k_gather_b<GCHUNK><<<GBLK, 256, 0, stream>>>(xb, dinv, offs, counts, csr2, g1, N);
    k_mgemm<128, false, MCHUNK><<<NBLK, 256, 0, stream>>>(g1, wt1, b1, a1r, nullptr, N);

    // --- layer 2 + fused mean ---
    k_gather_b<GCHUNK><<<GBLK, 256, 0, stream>>>(a1r, dinv, offs, counts, csr2, g2, N);
    k_mgemm<256, true, MCHUNK><<<NBLK, 256, 0, stream>>>(g2, wt2, b2, nullptr, partials, N);
    k_reduce<<<16, 256, 0, stream>>>(partials, p2, out, &flag[1], NBLK,
                                     1.0f / (float)N);
}

// Round 16
// 193.265 us; speedup vs baseline: 1.0945x; 1.0945x over previous
//
#include <hip/hip_runtime.h>

// ---------------------------------------------------------------------------
// DrugGCN, bf16-MFMA pipeline (R16 = R14 EXACT revert — champion 194.2us):
//   k_count: rank[e] = atomicAdd(&counts[dst],1)   (rank is free)
//   k_prep2: [fill_csr blocks | cvt_x blocks | cvt_w blocks] — one dispatch,
//            same sync point, complementary regimes (latency vs BW bound).
//   g1  = A_hat xb           (R8 gather: 16-lane groups, 4 strided nodes,
//   a1r = relu(g1@W1 + b1)    1-ahead pipeline — FROZEN)
//   g2  = A_hat a1r
//   out = mean_rows relu(g2@W2 + b2)  (B-stationary GEMM, fused col-reduce)
// R15 lesson: MCHUNK 8->4 regressed (B-register staging is a per-block fixed
// cost; halving work per block doubled it); ticket-fused reduce added a
// fence+serial tail. Both reverted. MCHUNK=8, separate reduce1/reduce2.
// ---------------------------------------------------------------------------

typedef __attribute__((ext_vector_type(8))) short short8;
typedef __attribute__((ext_vector_type(4))) float f32x4;

__device__ __forceinline__ float b2f(unsigned short u) {
    union { unsigned int i; float f; } c;
    c.i = ((unsigned int)u) << 16;
    return c.f;
}
__device__ __forceinline__ unsigned short f2b(float x) {
    union { float f; unsigned int i; } c;
    c.f = x;
    unsigned int r = c.i + 0x7FFFu + ((c.i >> 16) & 1u);   // RNE
    return (unsigned short)(r >> 16);
}

__device__ __forceinline__ int edge_idx(const void* ei, int is64, int which,
                                        int E, int e) {
    if (is64) return (int)((const long long*)ei)[(size_t)which * E + e];
    return ((const int*)ei)[(size_t)which * E + e];
}

// --- init: zero counts; block 0 also runs the sampled dtype detector --------
__global__ void k_init(const int* __restrict__ ei, int E, int* __restrict__ counts,
                       int* __restrict__ flag, int N) {
    int i = blockIdx.x * 256 + threadIdx.x;
    if (i < N) counts[i] = 0;
    if (blockIdx.x == 0) {
        __shared__ int anyv[4];
        int t = threadIdx.x;
        int v = 0;
#pragma unroll
        for (int r = 0; r < 4; ++r) {
            long long k = (long long)(t * 4 + r) * E >> 10;   // spread over [0,E)
            v |= ei[2 * (int)k + 1];
        }
        unsigned long long m = __ballot(v != 0);
        if ((t & 63) == 0) anyv[t >> 6] = (m != 0ull) ? 1 : 0;
        __syncthreads();
        if (t == 0) flag[0] = anyv[0] | anyv[1] | anyv[2] | anyv[3];
    }
}

// --- count + per-edge rank (atomicAdd return value is free) -----------------
__global__ void k_count(const void* __restrict__ ei, const int* __restrict__ flag,
                        int* __restrict__ counts, int* __restrict__ rank, int E) {
    int e = blockIdx.x * 256 + threadIdx.x;
    if (e >= E) return;
    int is64 = (*flag == 0);
    int d = edge_idx(ei, is64, 1, E, e);
    rank[e] = atomicAdd(&counts[d], 1);
}

// --- scan1 (+ fused dinv): per-block exclusive scan of counts ---------------
__global__ void k_scan1(const int* __restrict__ counts, int* __restrict__ offs,
                        int* __restrict__ blockSums, float* __restrict__ dinv,
                        int n) {
    __shared__ int tmp[256];
    int t = threadIdx.x;
    int i = blockIdx.x * 256 + t;
    int my = (i < n) ? counts[i] : 0;
    if (i < n) dinv[i] = rsqrtf(1.0f + (float)my);
    tmp[t] = my;
    __syncthreads();
    for (int off = 1; off < 256; off <<= 1) {
        int v = (t >= off) ? tmp[t - off] : 0;
        __syncthreads();
        tmp[t] += v;
        __syncthreads();
    }
    if (i < n) offs[i] = tmp[t] - my;
    if (t == 255) blockSums[blockIdx.x] = tmp[255];
}

// single-block 512-thread Hillis-Steele scan (exclusive), carry over tiles
__global__ void k_scan2(int* __restrict__ blockSums, int nb) {
    __shared__ int tmp[512];
    __shared__ int carry;
    int t = threadIdx.x;
    if (t == 0) carry = 0;
    __syncthreads();
    for (int base = 0; base < nb; base += 512) {
        int i = base + t;
        int my = (i < nb) ? blockSums[i] : 0;
        tmp[t] = my;
        __syncthreads();
        for (int off = 1; off < 512; off <<= 1) {
            int v = (t >= off) ? tmp[t - off] : 0;
            __syncthreads();
            tmp[t] += v;
            __syncthreads();
        }
        if (i < nb) blockSums[i] = carry + tmp[t] - my;   // exclusive
        __syncthreads();
        if (t == 0) carry += tmp[511];
        __syncthreads();
    }
}

__global__ void k_scan3(int* __restrict__ offs, const int* __restrict__ blockSums,
                        int n) {
    int i = blockIdx.x * 256 + threadIdx.x;
    if (i < n) offs[i] += blockSums[blockIdx.x];
}

// --- fused prep: [fill_csr | cvt_x | cvt_w] by blockIdx range ---------------
// fill: pos = offs[d] + rank[e]  (atomic-free, offs finalized by scan3)
// cvt_x: x f32 -> xb bf16 (float4/ushort4)
// cvt_w: W[k][n] f32 -> WT[n][k] bf16 (both weights)
__global__ void k_prep2(const void* __restrict__ ei, const int* __restrict__ flag,
                        const float* __restrict__ dinv,
                        const int* __restrict__ offs, const int* __restrict__ rank,
                        int2* __restrict__ csr2, int E, int FB,
                        const float* __restrict__ x, unsigned short* __restrict__ xb,
                        int n4x, int XB,
                        const float* __restrict__ W1, const float* __restrict__ W2,
                        unsigned short* __restrict__ wt1,
                        unsigned short* __restrict__ wt2) {
    const int b = blockIdx.x;
    if (b < FB) {                                   // --- CSR fill ---
        int e = b * 256 + threadIdx.x;
        if (e >= E) return;
        int is64 = (*flag == 0);
        int s = edge_idx(ei, is64, 0, E, e);
        int d = edge_idx(ei, is64, 1, E, e);
        int pos = offs[d] + rank[e];
        csr2[pos] = make_int2(s, __float_as_int(dinv[s] * dinv[d]));
    } else if (b < FB + XB) {                       // --- x -> bf16 ---
        int i = (b - FB) * 256 + threadIdx.x;
        if (i >= n4x) return;
        float4 v = reinterpret_cast<const float4*>(x)[i];
        ushort4 o;
        o.x = f2b(v.x); o.y = f2b(v.y); o.z = f2b(v.z); o.w = f2b(v.w);
        reinterpret_cast<ushort4*>(xb)[i] = o;
    } else {                                        // --- weights -> WT bf16 ---
        int idx = (b - FB - XB) * 256 + threadIdx.x;
        if (idx < 128 * 128) {
            int k = idx >> 7, n = idx & 127;        // KOUT=128
            wt1[(size_t)n * 128 + k] = f2b(W1[idx]);
        } else if (idx < 128 * 128 + 128 * 256) {
            int i2 = idx - 128 * 128;
            int k = i2 >> 8, n = i2 & 255;          // KOUT=256
            wt2[(size_t)n * 128 + k] = f2b(W2[i2]);
        }
    }
}

// --- CSR gather (R8 EXACT: 16-lane groups, strided nodes, 1-ahead pipe) -----
// g[d] = dd^2 h[d] + sum_e w_e h[s_e];  16 lanes/node (short8 = 16B/lane),
// 16 groups/block, CHUNK nodes per group. 1-ahead prefetch of (pair, row).
template <int CHUNK>
__global__ __launch_bounds__(256) void k_gather_b(const unsigned short* __restrict__ h,
                                                  const float* __restrict__ dinv,
                                                  const int* __restrict__ offs,
                                                  const int* __restrict__ counts,
                                                  const int2* __restrict__ csr2,
                                                  unsigned short* __restrict__ g,
                                                  int N) {
    const int grp = threadIdx.x >> 4, l16 = threadIdx.x & 15;
    const short8* h8 = reinterpret_cast<const short8*>(h);
    const int base = blockIdx.x * (CHUNK * 16) + grp;

    for (int i = 0; i < CHUNK; ++i) {
        const int node = base + i * 16;
        if (node >= N) break;               // uniform across the 16-lane group
        const float dd = dinv[node];
        const float w0 = dd * dd;
        const size_t rowu = (size_t)node * 16 + l16;
        short8 sv = h8[rowu];
        float a[8];
#pragma unroll
        for (int j = 0; j < 8; ++j) a[j] = b2f((unsigned short)sv[j]) * w0;

        const int beg = offs[node], cnt = counts[node];
        if (cnt > 0) {
            int2 p = csr2[beg];
            short8 v = h8[(size_t)p.x * 16 + l16];
            for (int e = 1; e < cnt; ++e) {
                int2 pn = csr2[beg + e];                       // next pair
                short8 vn = h8[(size_t)pn.x * 16 + l16];       // next row (issued
                float w = __int_as_float(p.y);                 //  before acc wait)
#pragma unroll
                for (int j = 0; j < 8; ++j)
                    a[j] = fmaf(b2f((unsigned short)v[j]), w, a[j]);
                p = pn; v = vn;
            }
            float w = __int_as_float(p.y);
#pragma unroll
            for (int j = 0; j < 8; ++j)
                a[j] = fmaf(b2f((unsigned short)v[j]), w, a[j]);
        }
        short8 o;
#pragma unroll
        for (int j = 0; j < 8; ++j) o[j] = (short)f2b(a[j]);
        reinterpret_cast<short8*>(g)[rowu] = o;
    }
}

// --- B-stationary MFMA GEMM (R7/R8 body; MCHUNK=8) --------------------------
// Fragment mapping (16x16x32, m89-verified): A: row=lane&15, k=(lane>>4)*8+j;
// B: col=lane&15 (WT row), same k; D: col=lane&15, row=(lane>>4)*4+r.
template <int KOUT, bool REDUCE, int CHUNK>
__global__ __launch_bounds__(256) void k_mgemm(const unsigned short* __restrict__ A,
                                               const unsigned short* __restrict__ WT,
                                               const float* __restrict__ bias,
                                               unsigned short* __restrict__ C,
                                               float* __restrict__ partials, int N) {
    constexpr int NFW = KOUT / 64;       // col-frags per wave (2 or 4)
    const int tid = threadIdx.x;
    const int wave = tid >> 6, lane = tid & 63;
    const int l15 = lane & 15, lg = lane >> 4;
    const int colbase = wave * (KOUT / 4);

    short8 breg[NFW][4];
    float bv[NFW];
#pragma unroll
    for (int nf = 0; nf < NFW; ++nf) {
        int col = colbase + nf * 16 + l15;
        bv[nf] = bias[col];
#pragma unroll
        for (int kk = 0; kk < 4; ++kk)
            breg[nf][kk] = *reinterpret_cast<const short8*>(
                WT + (size_t)col * 128 + kk * 32 + lg * 8);
    }

    float psum[NFW];
#pragma unroll
    for (int nf = 0; nf < NFW; ++nf) psum[nf] = 0.f;

    const int NT = (N + 15) / 16;
    const int t0 = blockIdx.x * CHUNK;
    const int tend = (t0 + CHUNK < NT) ? t0 + CHUNK : NT;

#pragma unroll 2
    for (int t = t0; t < tend; ++t) {
        const int rows = t * 16;
        const int arow = rows + l15;
        short8 a[4];
        const bool rv = arow < N;
#pragma unroll
        for (int kk = 0; kk < 4; ++kk)
            a[kk] = rv ? *reinterpret_cast<const short8*>(
                             A + (size_t)arow * 128 + kk * 32 + lg * 8)
                       : (short8){0, 0, 0, 0, 0, 0, 0, 0};

        f32x4 acc[NFW];
#pragma unroll
        for (int nf = 0; nf < NFW; ++nf) acc[nf] = (f32x4){0.f, 0.f, 0.f, 0.f};
#pragma unroll
        for (int kk = 0; kk < 4; ++kk)
#pragma unroll
            for (int nf = 0; nf < NFW; ++nf)
                acc[nf] = __builtin_amdgcn_mfma_f32_16x16x32_bf16(
                    a[kk], breg[nf][kk], acc[nf], 0, 0, 0);

        if (!REDUCE) {
#pragma unroll
            for (int nf = 0; nf < NFW; ++nf) {
                int col = colbase + nf * 16 + l15;
#pragma unroll
                for (int r = 0; r < 4; ++r) {
                    int rr = rows + lg * 4 + r;
                    if (rr < N)
                        C[(size_t)rr * KOUT + col] =
                            f2b(fmaxf(acc[nf][r] + bv[nf], 0.f));
                }
            }
        } else {
#pragma unroll
            for (int nf = 0; nf < NFW; ++nf) {
#pragma unroll
                for (int r = 0; r < 4; ++r) {
                    int rr = rows + lg * 4 + r;
                    if (rr < N) psum[nf] += fmaxf(acc[nf][r] + bv[nf], 0.f);
                }
            }
        }
    }

    if (REDUCE) {
#pragma unroll
        for (int nf = 0; nf < NFW; ++nf) {
            float s = psum[nf];
            s += __shfl_xor(s, 16);
            s += __shfl_xor(s, 32);
            if (lg == 0)
                partials[(size_t)blockIdx.x * KOUT + colbase + nf * 16 + l15] = s;
        }
    }
}

// --- partials reduction: [NB][256] -> [16][256] -> out[256]*invN ------------
__global__ void k_reduce1(const float* __restrict__ partials, float* __restrict__ p2,
                          int NB) {
    int c = threadIdx.x;
    float sum = 0.f;
    for (int r = blockIdx.x; r < NB; r += 16)
        sum += partials[(size_t)r * 256 + c];
    p2[blockIdx.x * 256 + c] = sum;
}

__global__ void k_reduce2(const float* __restrict__ p2, float* __restrict__ out,
                          float invN) {
    int c = threadIdx.x;
    float sum = 0.f;
#pragma unroll
    for (int b = 0; b < 16; ++b) sum += p2[b * 256 + c];
    out[c] = sum * invN;
}

// ---------------------------------------------------------------------------
extern "C" void kernel_launch(void* const* d_in, const int* in_sizes, int n_in,
                              void* d_out, int out_size, void* d_ws, size_t ws_size,
                              hipStream_t stream) {
    const float* x  = (const float*)d_in[0];
    const void*  ei = d_in[1];
    const float* W1 = (const float*)d_in[2];
    const float* b1 = (const float*)d_in[3];
    const float* W2 = (const float*)d_in[4];
    const float* b2 = (const float*)d_in[5];
    float* out = (float*)d_out;

    const int N = in_sizes[0] / 128;   // 100000
    const int E = in_sizes[1] / 2;     // 600000
    const int nb = (N + 255) / 256;
    constexpr int GCHUNK = 4;          // R8 values — proven optimum
    constexpr int MCHUNK = 8;          // R15's 4 regressed (B-staging amortization)
    const int NT = (N + 15) / 16;
    const int NBLK = (NT + MCHUNK - 1) / MCHUNK;              // gemm blocks
    const int GBLK = (N + GCHUNK * 16 - 1) / (GCHUNK * 16);   // gather blocks
    const int FB = (E + 255) / 256;                           // fill blocks
    const int XB = (N * 32 + 255) / 256;                      // cvt_x blocks
    const int WB = (128 * 384 + 255) / 256;                   // cvt_w blocks

    char* ws = (char*)d_ws;
    size_t off = 0;
    auto alloc = [&](size_t bytes) {
        char* p = ws + off;
        off += (bytes + 255) & ~(size_t)255;
        return p;
    };
    int*            flag      = (int*)alloc(4);
    int*            counts    = (int*)alloc((size_t)N * 4);
    int*            offs      = (int*)alloc((size_t)N * 4);
    int*            blockSums = (int*)alloc((size_t)nb * 4);
    float*          dinv      = (float*)alloc((size_t)N * 4);
    int*            rank      = (int*)alloc((size_t)E * 4);
    int2*           csr2      = (int2*)alloc((size_t)E * 8);
    float*          partials  = (float*)alloc((size_t)NBLK * 256 * 4);
    float*          p2        = (float*)alloc((size_t)16 * 256 * 4);
    unsigned short* wt1       = (unsigned short*)alloc((size_t)128 * 128 * 2);
    unsigned short* wt2       = (unsigned short*)alloc((size_t)256 * 128 * 2);
    unsigned short* xb        = (unsigned short*)alloc((size_t)N * 128 * 2);
    unsigned short* g1        = (unsigned short*)alloc((size_t)N * 128 * 2);
    unsigned short* a1r       = (unsigned short*)alloc((size_t)N * 128 * 2);
    unsigned short* g2        = xb;    // xb dead after gather1

    // --- CSR build: init -> count(+rank) -> scan -> fused prep ---
    k_init<<<nb, 256, 0, stream>>>((const int*)ei, E, counts, flag, N);
    k_count<<<(E + 255) / 256, 256, 0, stream>>>(ei, flag, counts, rank, E);
    k_scan1<<<nb, 256, 0, stream>>>(counts, offs, blockSums, dinv, N);
    k_scan2<<<1, 512, 0, stream>>>(blockSums, nb);
    k_scan3<<<nb, 256, 0, stream>>>(offs, blockSums, N);
    k_prep2<<<FB + XB + WB, 256, 0, stream>>>(ei, flag, dinv, offs, rank, csr2,
                                              E, FB, x, xb, N * 32, XB,
                                              W1, W2, wt1, wt2);

    // --- layer 1 ---
    k_gather_b<GCHUNK><<<GBLK, 256, 0, stream>>>(xb, dinv, offs, counts, csr2, g1, N);
    k_mgemm<128, false, MCHUNK><<<NBLK, 256, 0, stream>>>(g1, wt1, b1, a1r, nullptr, N);

    // --- layer 2 + fused mean ---
    k_gather_b<GCHUNK><<<GBLK, 256, 0, stream>>>(a1r, dinv, offs, counts, csr2, g2, N);
    k_mgemm<256, true, MCHUNK><<<NBLK, 256, 0, stream>>>(g2, wt2, b2, nullptr, partials, N);
    k_reduce1<<<16, 256, 0, stream>>>(partials, p2, NBLK);
    k_reduce2<<<1, 256, 0, stream>>>(p2, out, 1.0f / (float)N);
}